// Round 9
// baseline (538.899 us; speedup 1.0000x reference)
//
#include <hip/hip_runtime.h>

#define N_NODES  50000
#define R_REL    3
#define E_EDGES  50000
#define EP_EDGES 100000
#define ELL_CAP  32

typedef __attribute__((ext_vector_type(8))) short  short8;
typedef __attribute__((ext_vector_type(8))) unsigned short ushort8;
typedef __attribute__((ext_vector_type(4))) float  floatx4;

static inline int cdiv_h(int a, int b) { return (a + b - 1) / b; }

__device__ inline unsigned short f2b(float f) {
    union { float f; unsigned u; } v; v.f = f;
    return (unsigned short)((v.u + 0x7FFF + ((v.u >> 16) & 1)) >> 16);
}
__device__ inline float b2f(unsigned short h) {
    union { unsigned u; float f; } v; v.u = ((unsigned)h) << 16;
    return v.f;
}

#define GLDS16(gp, lp) __builtin_amdgcn_global_load_lds( \
    (const __attribute__((address_space(1))) void*)(gp), \
    (__attribute__((address_space(3))) void*)(lp), 16, 0, 0)

// ---------------- degree count + ELL fill ----------------
__global__ void count_fill_kernel(const int* __restrict__ src, const int* __restrict__ dst,
                                  int* __restrict__ outcnt, int* __restrict__ incnt,
                                  int* __restrict__ ell) {
    int i = blockIdx.x * blockDim.x + threadIdx.x;
    if (i >= R_REL * E_EDGES) return;
    int r = i / E_EDGES;
    int s = src[i], d = dst[i];
    atomicAdd(&outcnt[r * N_NODES + s], 1);
    int k = atomicAdd(&incnt[r * N_NODES + d], 1);
    if (k < ELL_CAP)
        ell[((size_t)(r * N_NODES + d) << 5) + k] = s;
}

// ---------------- fused aux pass: norms + x->bf16 + weight prep + compaction ------------
//   [0, AUX_NORM)            : sn/dn = rsqrt(max(cnt,1))     (outcnt/incnt contiguous)
//   [AUX_NORM, +AUX_F2B)     : x fp32 -> bf16, 8 elems/thread
//   [.., +AUX_PREP)          : weight transposes (4 layers + Wp1) + bsum[960]
//   [AUX_CMP_BASE, +AUX_CMP) : per-(rel,node) out-edge compaction, WAVE-AGGREGATED
//     atomics (round-7 lesson: 95K same-address atomicAdds on 3 counters = 1.1ms
//     serialization; ballot+popcount -> 1 atomic/wave = ~50us aux, round 8 verified).
#define AUX_NORM 300000
#define AUX_F2B  3200000
#define AUX_PREP 1319872
#define CMP_NPAD 50048
#define AUX_CMP  (3 * CMP_NPAD)
#define AUX_CMP_BASE 4819904   // (AUX_NORM+AUX_F2B+AUX_PREP=4819872) aligned up to x64
__global__ void aux_kernel(
        const int* __restrict__ cnt, float* __restrict__ nrm,
        const float* __restrict__ x, unsigned short* __restrict__ xb,
        const float* __restrict__ W0, const float* __restrict__ W1,
        const float* __restrict__ W2, const float* __restrict__ W3,
        const float* __restrict__ Wp1,
        const float* __restrict__ B0, const float* __restrict__ B1,
        const float* __restrict__ B2, const float* __restrict__ B3,
        unsigned short* __restrict__ Wt0, unsigned short* __restrict__ Wt1,
        unsigned short* __restrict__ Wt2, unsigned short* __restrict__ Wt3,
        unsigned short* __restrict__ But, float* __restrict__ bsum,
        int* __restrict__ csize, int* __restrict__ cmap,
        int* __restrict__ rlist, float* __restrict__ snc) {
    int gi = blockIdx.x * blockDim.x + threadIdx.x;
    if (gi < AUX_NORM) {
        nrm[gi] = rsqrtf(fmaxf((float)cnt[gi], 1.0f));
        return;
    }
    if (gi < AUX_NORM + AUX_F2B) {
        int t = gi - AUX_NORM;
        float4 a = ((const float4*)x)[2 * t];
        float4 b = ((const float4*)x)[2 * t + 1];
        ushort8 o;
        o[0] = f2b(a.x); o[1] = f2b(a.y); o[2] = f2b(a.z); o[3] = f2b(a.w);
        o[4] = f2b(b.x); o[5] = f2b(b.y); o[6] = f2b(b.z); o[7] = f2b(b.w);
        ((ushort8*)xb)[t] = o;
        return;
    }
    if (gi < AUX_NORM + AUX_F2B + AUX_PREP) {
        int i = gi - AUX_NORM - AUX_F2B;
        if (i < 786432) {                       // L0: K=512 dout=512 rows=1536
            int k = i & 511, nall = i >> 9, r = nall >> 9, n = nall & 511;
            Wt0[i] = f2b(W0[(((size_t)r << 9) + k) * 512 + n]);
        } else if (i < 1179648) {               // L1: K=512 dout=256 rows=768
            int j = i - 786432;
            int k = j & 511, nall = j >> 9, r = nall >> 8, n = nall & 255;
            Wt1[j] = f2b(W1[(((size_t)r << 9) + k) * 256 + n]);
        } else if (i < 1277952) {               // L2: K=256 dout=128 rows=384
            int j = i - 1179648;
            int k = j & 255, nall = j >> 8, r = nall >> 7, n = nall & 127;
            Wt2[j] = f2b(W2[(((size_t)r << 8) + k) * 128 + n]);
        } else if (i < 1310720) {               // L3: K=128 dout=64 rows=256 (pad 192..255)
            int j = i - 1277952;
            int k = j & 127, nall = j >> 7, r = nall >> 6, n = nall & 63;
            Wt3[j] = (r < R_REL) ? f2b(W3[(((size_t)r << 7) + k) * 64 + n]) : (unsigned short)0;
        } else if (i < 1318912) {               // Wp1 -> But[128][64]
            int j = i - 1310720;
            int k = j & 63, jo = j >> 6, jj = jo & 63, half = jo >> 6;
            But[j] = f2b(Wp1[(size_t)(half * 64 + k) * 64 + jj]);
        } else {                                // bsum[960]
            int j = i - 1318912;
            const float* B; int f, dout;
            if (j < 512)      { B = B0; f = j;       dout = 512; }
            else if (j < 768) { B = B1; f = j - 512; dout = 256; }
            else if (j < 896) { B = B2; f = j - 768; dout = 128; }
            else              { B = B3; f = j - 896; dout = 64;  }
            bsum[j] = B[f] + B[dout + f] + B[2 * dout + f];
        }
        return;
    }
    if (gi < AUX_CMP_BASE) return;              // alignment gap
    int q = gi - AUX_CMP_BASE;
    if (q >= AUX_CMP) return;
    int r = q / CMP_NPAD;
    int n = q - r * CMP_NPAD;
    bool active = false; int cq = 0;
    if (n < N_NODES) {
        cq = cnt[r * N_NODES + n];              // outcnt[r][n]
        active = cq > 0;
    }
    unsigned long long mask = __ballot(active);
    if (mask == 0ULL) return;
    int lane = threadIdx.x & 63;                // wave-aligned base => lane == q%64
    int tot = __popcll(mask);
    int leader = __builtin_ctzll(mask);
    int base = 0;
    if (lane == leader) base = atomicAdd(&csize[r], tot);
    base = __shfl(base, leader, 64);
    if (active) {
        int c = base + __popcll(mask & ((1ULL << lane) - 1ULL));
        cmap[r * N_NODES + n] = c;
        rlist[r * N_NODES + c] = n;
        snc[r * N_NODES + c] = rsqrtf((float)cq);
    }
}

// ---------------- ELL -> compact-index remap (after aux; cmap complete) ----------------
__global__ void remap_kernel(const int* __restrict__ incnt, const int* __restrict__ cmap,
                             const int* __restrict__ ell, int* __restrict__ ellc) {
    int i = blockIdx.x * blockDim.x + threadIdx.x;
    if (i >= R_REL * N_NODES) return;
    int nr = incnt[i];
    nr = nr < ELL_CAP ? nr : ELL_CAP;
    int r = i / N_NODES;
    size_t base = (size_t)i << 5;
    for (int k = 0; k < nr; ++k)
        ellc[base + k] = cmap[r * N_NODES + ell[base + k]];
}

// ---------------- compacted MFMA GEMM (L0-L2): per-rel, only rows with out-edges --------
// Proven 128^2/BK=64 structure (frozen). grid.z = rel. M = csize[z] (device value;
// excess m-blocks exit). A rows gathered via rlist. C compact [z][row][dout].
__global__ __launch_bounds__(256) void gemm_bf16_cmp(
        const unsigned short* __restrict__ A, const unsigned short* __restrict__ Bt,
        unsigned short* __restrict__ C, const float* __restrict__ snc,
        const int* __restrict__ rlist, const int* __restrict__ csize,
        int K, int dout) {
    __shared__ unsigned short As[8192];   // [128][64]
    __shared__ unsigned short Bs[8192];   // [128][64]

    const int z = blockIdx.z;
    const int csz = csize[z];
    const int nN = gridDim.x, nM = gridDim.y;
    int p = blockIdx.y * nN + blockIdx.x;
    const int nig = nN << 3;
    int group = p / nig;
    int rem = p - group * nig;
    int gs = nM - (group << 3); if (gs > 8) gs = 8;
    int mb = (group << 3) + rem % gs;
    int nb = rem / gs;
    const int m0 = mb * 128, n0 = nb * 128;
    if (m0 >= csz) return;                 // uniform exit: compacted rows exhausted

    const int tid  = threadIdx.x;
    const int w    = tid >> 6;
    const int lane = tid & 63;
    const int wm   = w & 1;
    const int wn   = w >> 1;
    const int lrow8 = lane >> 3;
    const int cs    = ((lane & 7) ^ lrow8) << 3;

    size_t abase[4];
#pragma unroll
    for (int i = 0; i < 4; ++i) {
        int ridx = m0 + i * 32 + 8 * w + lrow8;
        if (ridx >= csz) ridx = csz - 1;
        abase[i] = (size_t)rlist[z * N_NODES + ridx] * K;
    }
    const unsigned short* Btz = Bt + (size_t)z * dout * K;

    floatx4 acc[4][4];
#pragma unroll
    for (int i = 0; i < 4; ++i)
#pragma unroll
        for (int j = 0; j < 4; ++j) acc[i][j] = (floatx4){0.f, 0.f, 0.f, 0.f};

    const int mrow  = lane & 15;
    const int phys0 = ((lane >> 4) ^ (lane & 7)) << 3;
    const int phys1 = phys0 ^ 32;

    for (int k0 = 0; k0 < K; k0 += 64) {
#pragma unroll
        for (int i = 0; i < 4; ++i)
            GLDS16(A + abase[i] + k0 + cs, As + (i * 32 + 8 * w) * 64);
#pragma unroll
        for (int i = 0; i < 4; ++i) {
            int rr = i * 32 + 8 * w + lrow8;
            GLDS16(Btz + (size_t)(n0 + rr) * K + k0 + cs, Bs + (i * 32 + 8 * w) * 64);
        }
        __syncthreads();

#pragma unroll
        for (int h = 0; h < 2; ++h) {
            const int ph = h ? phys1 : phys0;
            short8 a[4], b[4];
#pragma unroll
            for (int nt = 0; nt < 4; ++nt)
                b[nt] = *(const short8*)&Bs[(wn * 64 + nt * 16 + mrow) * 64 + ph];
#pragma unroll
            for (int mt = 0; mt < 4; ++mt)
                a[mt] = *(const short8*)&As[(wm * 64 + mt * 16 + mrow) * 64 + ph];
#pragma unroll
            for (int mt = 0; mt < 4; ++mt)
#pragma unroll
                for (int nt = 0; nt < 4; ++nt)
                    acc[mt][nt] = __builtin_amdgcn_mfma_f32_16x16x32_bf16(a[mt], b[nt],
                                                                          acc[mt][nt], 0, 0, 0);
        }
        __syncthreads();
    }

    const int col = n0 + wn * 64 + (lane & 15);
    const int rb0 = m0 + wm * 64 + (lane >> 4) * 4;
    const size_t cbase = (size_t)z * N_NODES * dout;
#pragma unroll
    for (int mt = 0; mt < 4; ++mt) {
        float4 rsv = *(const float4*)&snc[z * N_NODES + rb0 + mt * 16];
        const float* rsp = (const float*)&rsv;
#pragma unroll
        for (int reg = 0; reg < 4; ++reg) {
            int row = rb0 + mt * 16 + reg;
            if (row < csz) {
                float rs = rsp[reg];
#pragma unroll
                for (int nt = 0; nt < 4; ++nt)
                    C[cbase + (size_t)row * dout + col + nt * 16] = f2b(acc[mt][nt][reg] * rs);
            }
        }
    }
}

// ---------------- fused MFMA GEMM 128x128 (full rows; L3 + UV) ----------------
__global__ __launch_bounds__(256) void gemm_bf16_fused(
        const unsigned short* __restrict__ A, const unsigned short* __restrict__ Bt,
        unsigned short* __restrict__ C, const float* __restrict__ sn,
        int M, int K, int NdPad, int dout) {
    __shared__ unsigned short As[8192];   // [128][64]
    __shared__ unsigned short Bs[8192];   // [128][64]

    const int nN = gridDim.x, nM = gridDim.y;
    int p = blockIdx.y * nN + blockIdx.x;
    const int nig = nN << 3;
    int group = p / nig;
    int rem = p - group * nig;
    int gs = nM - (group << 3); if (gs > 8) gs = 8;
    int mb = (group << 3) + rem % gs;
    int nb = rem / gs;
    const int m0 = mb * 128, n0 = nb * 128;

    const int tid  = threadIdx.x;
    const int w    = tid >> 6;
    const int lane = tid & 63;
    const int wm   = w & 1;
    const int wn   = w >> 1;
    const int lrow8 = lane >> 3;
    const int cs    = ((lane & 7) ^ lrow8) << 3;

    floatx4 acc[4][4];
#pragma unroll
    for (int i = 0; i < 4; ++i)
#pragma unroll
        for (int j = 0; j < 4; ++j) acc[i][j] = (floatx4){0.f, 0.f, 0.f, 0.f};

    const int mrow  = lane & 15;
    const int phys0 = ((lane >> 4) ^ (lane & 7)) << 3;
    const int phys1 = phys0 ^ 32;

    for (int k0 = 0; k0 < K; k0 += 64) {
#pragma unroll
        for (int i = 0; i < 4; ++i) {
            int rr = i * 32 + 8 * w + lrow8;
            GLDS16(A  + (size_t)(m0 + rr) * K + k0 + cs, As + (i * 32 + 8 * w) * 64);
        }
#pragma unroll
        for (int i = 0; i < 4; ++i) {
            int rr = i * 32 + 8 * w + lrow8;
            GLDS16(Bt + (size_t)(n0 + rr) * K + k0 + cs, Bs + (i * 32 + 8 * w) * 64);
        }
        __syncthreads();

#pragma unroll
        for (int h = 0; h < 2; ++h) {
            const int ph = h ? phys1 : phys0;
            short8 a[4], b[4];
#pragma unroll
            for (int nt = 0; nt < 4; ++nt)
                b[nt] = *(const short8*)&Bs[(wn * 64 + nt * 16 + mrow) * 64 + ph];
#pragma unroll
            for (int mt = 0; mt < 4; ++mt)
                a[mt] = *(const short8*)&As[(wm * 64 + mt * 16 + mrow) * 64 + ph];
#pragma unroll
            for (int mt = 0; mt < 4; ++mt)
#pragma unroll
                for (int nt = 0; nt < 4; ++nt)
                    acc[mt][nt] = __builtin_amdgcn_mfma_f32_16x16x32_bf16(a[mt], b[nt],
                                                                          acc[mt][nt], 0, 0, 0);
        }
        __syncthreads();
    }

    const int colb = n0 + wn * 64;
    const int r_quad = colb / dout;
    if (sn && r_quad >= R_REL) return;
    const int col = colb + (lane & 15);
    const int rb0 = m0 + wm * 64 + (lane >> 4) * 4;
#pragma unroll
    for (int mt = 0; mt < 4; ++mt) {
        float4 rsv;
        if (sn) rsv = *(const float4*)&sn[(size_t)r_quad * N_NODES + rb0 + mt * 16];
        else    rsv = (float4){1.f, 1.f, 1.f, 1.f};
        const float* rsp = (const float*)&rsv;
#pragma unroll
        for (int reg = 0; reg < 4; ++reg) {
            int row = rb0 + mt * 16 + reg;
            if (row < M) {
                float rs = rsp[reg];
#pragma unroll
                for (int nt = 0; nt < 4; ++nt)
                    C[(size_t)row * NdPad + col + nt * 16] = f2b(acc[mt][nt][reg] * rs);
            }
        }
    }
}

// ---------------- fused 3-relation ELL gather (QUAD-chunk) ----------------
// Each thread handles 4 ushort8 chunks (64B/lane): c, c+h8, c+2*h8, c+3*h8, h8=d8/4.
// vs dual-chunk: halves threads/node again -> halves redundant incnt/dn/ell broadcast
// loads and doubles payload per dependent ell->row chain. Lane groups still cover
// contiguous chunk ranges -> coalescing preserved. Per-element accumulation order
// unchanged (per-rel t accum, one dn multiply) -> bitwise-identical output.
// mode==1: ell holds COMPACT row indices (pre-remapped), hr is [r][N][dout].
// mode==0: ell holds node indices, hr legacy row-major [s][3*dout] (stride S8).
__global__ void gather3_kernel(const unsigned short* __restrict__ hr, int S8, int d8,
                               const int* __restrict__ ell, const int* __restrict__ incnt,
                               const float* __restrict__ dn, const float* __restrict__ bsum,
                               unsigned short* __restrict__ outh,
                               int lgh, int total, int do_relu, int mode) {
    int i = blockIdx.x * blockDim.x + threadIdx.x;
    if (i >= total) return;
    int d = i >> lgh;
    int c = i & ((1 << lgh) - 1);
    int h8 = 1 << lgh;                       // d8/4
    float acc[4][8];
#pragma unroll
    for (int u = 0; u < 4; ++u)
#pragma unroll
        for (int j = 0; j < 8; ++j) acc[u][j] = 0.f;
    const ushort8* hr8 = (const ushort8*)hr;
#pragma unroll
    for (int r = 0; r < R_REL; ++r) {
        int nr = incnt[r * N_NODES + d];
        nr = nr < ELL_CAP ? nr : ELL_CAP;
        size_t base = (size_t)(r * N_NODES + d) << 5;
        float t[4][8];
#pragma unroll
        for (int u = 0; u < 4; ++u)
#pragma unroll
            for (int j = 0; j < 8; ++j) t[u][j] = 0.f;
        for (int k = 0; k < nr; ++k) {
            int s = ell[base + k];
            size_t rowb;
            if (mode)
                rowb = ((size_t)(r * N_NODES + s)) * d8 + c;      // s = compact idx
            else
                rowb = (size_t)s * S8 + r * d8 + c;               // s = node idx
#pragma unroll
            for (int u = 0; u < 4; ++u) {
                ushort8 v = hr8[rowb + u * h8];
#pragma unroll
                for (int j = 0; j < 8; ++j) t[u][j] += b2f(v[j]);
            }
        }
        float dnd = dn[r * N_NODES + d];
#pragma unroll
        for (int u = 0; u < 4; ++u)
#pragma unroll
            for (int j = 0; j < 8; ++j) acc[u][j] += dnd * t[u][j];
    }
#pragma unroll
    for (int u = 0; u < 4; ++u) {
        int f = (c + u * h8) << 3;
#pragma unroll
        for (int j = 0; j < 8; ++j) acc[u][j] += bsum[f + j];
    }
    if (do_relu) {
#pragma unroll
        for (int u = 0; u < 4; ++u)
#pragma unroll
            for (int j = 0; j < 8; ++j) acc[u][j] = fmaxf(acc[u][j], 0.f);
    }
    size_t ob = ((size_t)d << (lgh + 2)) + c;
#pragma unroll
    for (int u = 0; u < 4; ++u) {
        ushort8 o;
#pragma unroll
        for (int j = 0; j < 8; ++j) o[j] = f2b(acc[u][j]);
        ((ushort8*)outh)[ob + u * h8] = o;
    }
}

// ---------------- edge scores from UV ----------------
__global__ __launch_bounds__(256) void edge_score_kernel(
        const unsigned short* __restrict__ UV,
        const int* __restrict__ pos_src, const int* __restrict__ pos_dst,
        const int* __restrict__ neg_src, const int* __restrict__ neg_dst,
        const float* __restrict__ bp1, const float* __restrict__ Wp2,
        const float* __restrict__ bp2, float* __restrict__ outp) {
    __shared__ float sb[64], sw[64];
    int t = threadIdx.x;
    if (t < 64) { sb[t] = bp1[t]; sw[t] = Wp2[t]; }
    __syncthreads();
    int i = blockIdx.x * blockDim.x + t;
    if (i >= 2 * EP_EDGES) return;
    int s, d;
    if (i < EP_EDGES) { s = pos_src[i]; d = pos_dst[i]; }
    else              { s = neg_src[i - EP_EDGES]; d = neg_dst[i - EP_EDGES]; }
    const ushort8* UV8 = (const ushort8*)UV;
    float acc = bp2[0];
#pragma unroll
    for (int jv = 0; jv < 8; ++jv) {
        ushort8 u = UV8[(size_t)s * 16 + jv];
        ushort8 v = UV8[(size_t)d * 16 + 8 + jv];
#pragma unroll
        for (int j = 0; j < 8; ++j) {
            float z = b2f(u[j]) + b2f(v[j]) + sb[jv * 8 + j];
            acc = fmaf(fmaxf(z, 0.f), sw[jv * 8 + j], acc);
        }
    }
    outp[i] = acc;
}

extern "C" void kernel_launch(void* const* d_in, const int* in_sizes, int n_in,
                              void* d_out, int out_size, void* d_ws, size_t ws_size,
                              hipStream_t stream) {
    const float* x       = (const float*)d_in[0];
    const int*   rel_src = (const int*)d_in[1];
    const int*   rel_dst = (const int*)d_in[2];
    const int*   pos_src = (const int*)d_in[3];
    const int*   pos_dst = (const int*)d_in[4];
    const int*   neg_src = (const int*)d_in[5];
    const int*   neg_dst = (const int*)d_in[6];
    const float* W[4]    = {(const float*)d_in[7],  (const float*)d_in[9],
                            (const float*)d_in[11], (const float*)d_in[13]};
    const float* bias[4] = {(const float*)d_in[8],  (const float*)d_in[10],
                            (const float*)d_in[12], (const float*)d_in[14]};
    const float* Wp1 = (const float*)d_in[15];
    const float* bp1 = (const float*)d_in[16];
    const float* Wp2 = (const float*)d_in[17];
    const float* bp2 = (const float*)d_in[18];
    float* out = (float*)d_out;

    // workspace layout (bf16 buffers padded +128 rows for OOB tile reads, BM=128)
    size_t NP = (size_t)(N_NODES + 128);
    unsigned short* xb  = (unsigned short*)d_ws;          // NP x 512 (reused for UV later)
    unsigned short* h0  = xb + NP * 512;                  // NP x 512
    unsigned short* h1  = h0 + NP * 512;                  // NP x 256
    unsigned short* hr  = h1 + NP * 256;                  // 3*N*512 max (compact or fused C)
    unsigned short* Wt0 = hr + (size_t)R_REL * N_NODES * 512;
    unsigned short* Wt1 = Wt0 + 786432;
    unsigned short* Wt2 = Wt1 + 393216;
    unsigned short* Wt3 = Wt2 + 98304;
    unsigned short* But = Wt3 + 32768;                    // 128*64
    float* bsum = (float*)(But + 128 * 64);               // 960 summed biases
    float* sn   = bsum + 960;                             // full norms (L3 path + dn)
    float* dn   = sn + (size_t)R_REL * N_NODES;
    int* outcnt = (int*)(dn + (size_t)R_REL * N_NODES);
    int* incnt  = outcnt + (size_t)R_REL * N_NODES;
    int* csize  = incnt + (size_t)R_REL * N_NODES;        // 4 ints (3 used)
    int* ell    = csize + 4;                              // 3*N*32 ints (node idx)
    int* cmap   = ell + (size_t)R_REL * N_NODES * ELL_CAP;
    int* rlist  = cmap + (size_t)R_REL * N_NODES;
    float* snc  = (float*)(rlist + (size_t)R_REL * N_NODES);  // 3N + 128 pad
    int* ellc   = (int*)(snc + (size_t)R_REL * N_NODES + 128); // 3*N*32 ints (compact idx)
    unsigned short* UV = xb;                              // N x 128 (after layers done)
    const unsigned short* Wt[4] = {Wt0, Wt1, Wt2, Wt3};
    const int boff[4] = {0, 512, 768, 896};

    hipMemsetAsync(outcnt, 0, sizeof(int) * (2 * R_REL * N_NODES + 4), stream);
    count_fill_kernel<<<cdiv_h(R_REL * E_EDGES, 256), 256, 0, stream>>>(
        rel_src, rel_dst, outcnt, incnt, ell);

    aux_kernel<<<cdiv_h(AUX_CMP_BASE + AUX_CMP, 256), 256, 0, stream>>>(
        outcnt, sn, x, xb,
        W[0], W[1], W[2], W[3], Wp1, bias[0], bias[1], bias[2], bias[3],
        Wt0, Wt1, Wt2, Wt3, But, bsum, csize, cmap, rlist, snc);

    remap_kernel<<<cdiv_h(R_REL * N_NODES, 256), 256, 0, stream>>>(incnt, cmap, ell, ellc);

    const int dims[5] = {512, 512, 256, 128, 64};
    unsigned short* hbufs[4] = {h0, h1, h0, h1};
    const unsigned short* hcur = xb;
    for (int l = 0; l < 4; ++l) {
        int din = dims[l], dout = dims[l + 1];
        unsigned short* hnext = hbufs[l];
        // quad-chunk: threads per node = dout/32, each handling 4 ushort8 chunks
        int lgh = (dout == 512) ? 4 : (dout == 256) ? 3 : (dout == 128) ? 2 : 1;
        int total = N_NODES << lgh;
        if (l < 3) {   // compacted path (dout >= 128)
            dim3 grid(dout / 128, cdiv_h(N_NODES, 128), R_REL);
            gemm_bf16_cmp<<<grid, 256, 0, stream>>>(hcur, Wt[l], hr, snc, rlist, csize,
                                                    din, dout);
            gather3_kernel<<<cdiv_h(total, 256), 256, 0, stream>>>(
                hr, dout / 8, dout / 8, ellc, incnt, dn, bsum + boff[l], hnext, lgh, total,
                1, 1);
        } else {       // L3: dout=64 < BN -> legacy full path (NdPad=256)
            dim3 grid(256 / 128, cdiv_h(N_NODES, 128));
            gemm_bf16_fused<<<grid, 256, 0, stream>>>(hcur, Wt[l], hr, sn, N_NODES, din,
                                                      256, dout);
            gather3_kernel<<<cdiv_h(total, 256), 256, 0, stream>>>(
                hr, 256 / 8, dout / 8, ell, incnt, dn, bsum + boff[l], hnext, lgh, total,
                0, 0);
        }
        hcur = hnext;
    }

    // UV = h_final @ [Wp1_top | Wp1_bot]  (M=N, K=64, Nd=128)
    dim3 uvgrid(1, cdiv_h(N_NODES, 128));
    gemm_bf16_fused<<<uvgrid, 256, 0, stream>>>(hcur, But, UV, nullptr, N_NODES, 64, 128, 128);

    edge_score_kernel<<<cdiv_h(2 * EP_EDGES, 256), 256, 0, stream>>>(
        UV, pos_src, pos_dst, neg_src, neg_dst, bp1, Wp2, bp2, out);
}

// Round 10
// 519.217 us; speedup vs baseline: 1.0379x; 1.0379x over previous
//
#include <hip/hip_runtime.h>

#define N_NODES  50000
#define R_REL    3
#define E_EDGES  50000
#define EP_EDGES 100000
#define ELL_CAP  32

typedef __attribute__((ext_vector_type(8))) short  short8;
typedef __attribute__((ext_vector_type(8))) unsigned short ushort8;
typedef __attribute__((ext_vector_type(4))) float  floatx4;

static inline int cdiv_h(int a, int b) { return (a + b - 1) / b; }

__device__ inline unsigned short f2b(float f) {
    union { float f; unsigned u; } v; v.f = f;
    return (unsigned short)((v.u + 0x7FFF + ((v.u >> 16) & 1)) >> 16);
}
__device__ inline float b2f(unsigned short h) {
    union { unsigned u; float f; } v; v.u = ((unsigned)h) << 16;
    return v.f;
}

#define GLDS16(gp, lp) __builtin_amdgcn_global_load_lds( \
    (const __attribute__((address_space(1))) void*)(gp), \
    (__attribute__((address_space(3))) void*)(lp), 16, 0, 0)

// ---------------- degree count + ELL fill ----------------
__global__ void count_fill_kernel(const int* __restrict__ src, const int* __restrict__ dst,
                                  int* __restrict__ outcnt, int* __restrict__ incnt,
                                  int* __restrict__ ell) {
    int i = blockIdx.x * blockDim.x + threadIdx.x;
    if (i >= R_REL * E_EDGES) return;
    int r = i / E_EDGES;
    int s = src[i], d = dst[i];
    atomicAdd(&outcnt[r * N_NODES + s], 1);
    int k = atomicAdd(&incnt[r * N_NODES + d], 1);
    if (k < ELL_CAP)
        ell[((size_t)(r * N_NODES + d) << 5) + k] = s;
}

// ---------------- fused aux pass: norms + x->bf16 + weight prep + compaction ------------
//   [0, AUX_NORM)            : sn/dn = rsqrt(max(cnt,1))     (outcnt/incnt contiguous)
//   [AUX_NORM, +AUX_F2B)     : x fp32 -> bf16, 8 elems/thread
//   [.., +AUX_PREP)          : weight transposes (4 layers + Wp1) + bsum[960]
//   [AUX_CMP_BASE, +AUX_CMP) : per-(rel,node) out-edge compaction, WAVE-AGGREGATED
//     atomics (round-7 lesson: 95K same-address atomicAdds on 3 counters = 1.1ms
//     serialization; ballot+popcount -> 1 atomic/wave, round-8 verified fix).
#define AUX_NORM 300000
#define AUX_F2B  3200000
#define AUX_PREP 1319872
#define CMP_NPAD 50048
#define AUX_CMP  (3 * CMP_NPAD)
#define AUX_CMP_BASE 4819904   // (AUX_NORM+AUX_F2B+AUX_PREP=4819872) aligned up to x64
__global__ void aux_kernel(
        const int* __restrict__ cnt, float* __restrict__ nrm,
        const float* __restrict__ x, unsigned short* __restrict__ xb,
        const float* __restrict__ W0, const float* __restrict__ W1,
        const float* __restrict__ W2, const float* __restrict__ W3,
        const float* __restrict__ Wp1,
        const float* __restrict__ B0, const float* __restrict__ B1,
        const float* __restrict__ B2, const float* __restrict__ B3,
        unsigned short* __restrict__ Wt0, unsigned short* __restrict__ Wt1,
        unsigned short* __restrict__ Wt2, unsigned short* __restrict__ Wt3,
        unsigned short* __restrict__ But, float* __restrict__ bsum,
        int* __restrict__ csize, int* __restrict__ cmap,
        int* __restrict__ rlist, float* __restrict__ snc) {
    int gi = blockIdx.x * blockDim.x + threadIdx.x;
    if (gi < AUX_NORM) {
        nrm[gi] = rsqrtf(fmaxf((float)cnt[gi], 1.0f));
        return;
    }
    if (gi < AUX_NORM + AUX_F2B) {
        int t = gi - AUX_NORM;
        float4 a = ((const float4*)x)[2 * t];
        float4 b = ((const float4*)x)[2 * t + 1];
        ushort8 o;
        o[0] = f2b(a.x); o[1] = f2b(a.y); o[2] = f2b(a.z); o[3] = f2b(a.w);
        o[4] = f2b(b.x); o[5] = f2b(b.y); o[6] = f2b(b.z); o[7] = f2b(b.w);
        ((ushort8*)xb)[t] = o;
        return;
    }
    if (gi < AUX_NORM + AUX_F2B + AUX_PREP) {
        int i = gi - AUX_NORM - AUX_F2B;
        if (i < 786432) {                       // L0: K=512 dout=512 rows=1536
            int k = i & 511, nall = i >> 9, r = nall >> 9, n = nall & 511;
            Wt0[i] = f2b(W0[(((size_t)r << 9) + k) * 512 + n]);
        } else if (i < 1179648) {               // L1: K=512 dout=256 rows=768
            int j = i - 786432;
            int k = j & 511, nall = j >> 9, r = nall >> 8, n = nall & 255;
            Wt1[j] = f2b(W1[(((size_t)r << 9) + k) * 256 + n]);
        } else if (i < 1277952) {               // L2: K=256 dout=128 rows=384
            int j = i - 1179648;
            int k = j & 255, nall = j >> 8, r = nall >> 7, n = nall & 127;
            Wt2[j] = f2b(W2[(((size_t)r << 8) + k) * 128 + n]);
        } else if (i < 1310720) {               // L3: K=128 dout=64 rows=256 (pad 192..255)
            int j = i - 1277952;
            int k = j & 127, nall = j >> 7, r = nall >> 6, n = nall & 63;
            Wt3[j] = (r < R_REL) ? f2b(W3[(((size_t)r << 7) + k) * 64 + n]) : (unsigned short)0;
        } else if (i < 1318912) {               // Wp1 -> But[128][64]
            int j = i - 1310720;
            int k = j & 63, jo = j >> 6, jj = jo & 63, half = jo >> 6;
            But[j] = f2b(Wp1[(size_t)(half * 64 + k) * 64 + jj]);
        } else {                                // bsum[960]
            int j = i - 1318912;
            const float* B; int f, dout;
            if (j < 512)      { B = B0; f = j;       dout = 512; }
            else if (j < 768) { B = B1; f = j - 512; dout = 256; }
            else if (j < 896) { B = B2; f = j - 768; dout = 128; }
            else              { B = B3; f = j - 896; dout = 64;  }
            bsum[j] = B[f] + B[dout + f] + B[2 * dout + f];
        }
        return;
    }
    if (gi < AUX_CMP_BASE) return;              // alignment gap
    int q = gi - AUX_CMP_BASE;
    if (q >= AUX_CMP) return;
    int r = q / CMP_NPAD;
    int n = q - r * CMP_NPAD;
    bool active = false; int cq = 0;
    if (n < N_NODES) {
        cq = cnt[r * N_NODES + n];              // outcnt[r][n]
        active = cq > 0;
    }
    unsigned long long mask = __ballot(active);
    if (mask == 0ULL) return;
    int lane = threadIdx.x & 63;                // wave-aligned base => lane == q%64
    int tot = __popcll(mask);
    int leader = __builtin_ctzll(mask);
    int base = 0;
    if (lane == leader) base = atomicAdd(&csize[r], tot);
    base = __shfl(base, leader, 64);
    if (active) {
        int c = base + __popcll(mask & ((1ULL << lane) - 1ULL));
        cmap[r * N_NODES + n] = c;
        rlist[r * N_NODES + c] = n;
        snc[r * N_NODES + c] = rsqrtf((float)cq);
    }
}

// ---------------- ELL -> compact-index remap (after aux; cmap complete) ----------------
__global__ void remap_kernel(const int* __restrict__ incnt, const int* __restrict__ cmap,
                             const int* __restrict__ ell, int* __restrict__ ellc) {
    int i = blockIdx.x * blockDim.x + threadIdx.x;
    if (i >= R_REL * N_NODES) return;
    int nr = incnt[i];
    nr = nr < ELL_CAP ? nr : ELL_CAP;
    int r = i / N_NODES;
    size_t base = (size_t)i << 5;
    for (int k = 0; k < nr; ++k)
        ellc[base + k] = cmap[r * N_NODES + ell[base + k]];
}

// ---------------- compacted MFMA GEMM (L0-L2): per-rel, only rows with out-edges --------
// Proven 128^2/BK=64 structure (frozen). grid.z = rel. M = csize[z] (device value;
// excess m-blocks exit). A rows gathered via rlist. C compact [z][row][dout].
__global__ __launch_bounds__(256) void gemm_bf16_cmp(
        const unsigned short* __restrict__ A, const unsigned short* __restrict__ Bt,
        unsigned short* __restrict__ C, const float* __restrict__ snc,
        const int* __restrict__ rlist, const int* __restrict__ csize,
        int K, int dout) {
    __shared__ unsigned short As[8192];   // [128][64]
    __shared__ unsigned short Bs[8192];   // [128][64]

    const int z = blockIdx.z;
    const int csz = csize[z];
    const int nN = gridDim.x, nM = gridDim.y;
    int p = blockIdx.y * nN + blockIdx.x;
    const int nig = nN << 3;
    int group = p / nig;
    int rem = p - group * nig;
    int gs = nM - (group << 3); if (gs > 8) gs = 8;
    int mb = (group << 3) + rem % gs;
    int nb = rem / gs;
    const int m0 = mb * 128, n0 = nb * 128;
    if (m0 >= csz) return;                 // uniform exit: compacted rows exhausted

    const int tid  = threadIdx.x;
    const int w    = tid >> 6;
    const int lane = tid & 63;
    const int wm   = w & 1;
    const int wn   = w >> 1;
    const int lrow8 = lane >> 3;
    const int cs    = ((lane & 7) ^ lrow8) << 3;

    size_t abase[4];
#pragma unroll
    for (int i = 0; i < 4; ++i) {
        int ridx = m0 + i * 32 + 8 * w + lrow8;
        if (ridx >= csz) ridx = csz - 1;
        abase[i] = (size_t)rlist[z * N_NODES + ridx] * K;
    }
    const unsigned short* Btz = Bt + (size_t)z * dout * K;

    floatx4 acc[4][4];
#pragma unroll
    for (int i = 0; i < 4; ++i)
#pragma unroll
        for (int j = 0; j < 4; ++j) acc[i][j] = (floatx4){0.f, 0.f, 0.f, 0.f};

    const int mrow  = lane & 15;
    const int phys0 = ((lane >> 4) ^ (lane & 7)) << 3;
    const int phys1 = phys0 ^ 32;

    for (int k0 = 0; k0 < K; k0 += 64) {
#pragma unroll
        for (int i = 0; i < 4; ++i)
            GLDS16(A + abase[i] + k0 + cs, As + (i * 32 + 8 * w) * 64);
#pragma unroll
        for (int i = 0; i < 4; ++i) {
            int rr = i * 32 + 8 * w + lrow8;
            GLDS16(Btz + (size_t)(n0 + rr) * K + k0 + cs, Bs + (i * 32 + 8 * w) * 64);
        }
        __syncthreads();

#pragma unroll
        for (int h = 0; h < 2; ++h) {
            const int ph = h ? phys1 : phys0;
            short8 a[4], b[4];
#pragma unroll
            for (int nt = 0; nt < 4; ++nt)
                b[nt] = *(const short8*)&Bs[(wn * 64 + nt * 16 + mrow) * 64 + ph];
#pragma unroll
            for (int mt = 0; mt < 4; ++mt)
                a[mt] = *(const short8*)&As[(wm * 64 + mt * 16 + mrow) * 64 + ph];
#pragma unroll
            for (int mt = 0; mt < 4; ++mt)
#pragma unroll
                for (int nt = 0; nt < 4; ++nt)
                    acc[mt][nt] = __builtin_amdgcn_mfma_f32_16x16x32_bf16(a[mt], b[nt],
                                                                          acc[mt][nt], 0, 0, 0);
        }
        __syncthreads();
    }

    const int col = n0 + wn * 64 + (lane & 15);
    const int rb0 = m0 + wm * 64 + (lane >> 4) * 4;
    const size_t cbase = (size_t)z * N_NODES * dout;
#pragma unroll
    for (int mt = 0; mt < 4; ++mt) {
        float4 rsv = *(const float4*)&snc[z * N_NODES + rb0 + mt * 16];
        const float* rsp = (const float*)&rsv;
#pragma unroll
        for (int reg = 0; reg < 4; ++reg) {
            int row = rb0 + mt * 16 + reg;
            if (row < csz) {
                float rs = rsp[reg];
#pragma unroll
                for (int nt = 0; nt < 4; ++nt)
                    C[cbase + (size_t)row * dout + col + nt * 16] = f2b(acc[mt][nt][reg] * rs);
            }
        }
    }
}

// ---------------- fused MFMA GEMM 128x128 (full rows; L3 + UV) ----------------
__global__ __launch_bounds__(256) void gemm_bf16_fused(
        const unsigned short* __restrict__ A, const unsigned short* __restrict__ Bt,
        unsigned short* __restrict__ C, const float* __restrict__ sn,
        int M, int K, int NdPad, int dout) {
    __shared__ unsigned short As[8192];   // [128][64]
    __shared__ unsigned short Bs[8192];   // [128][64]

    const int nN = gridDim.x, nM = gridDim.y;
    int p = blockIdx.y * nN + blockIdx.x;
    const int nig = nN << 3;
    int group = p / nig;
    int rem = p - group * nig;
    int gs = nM - (group << 3); if (gs > 8) gs = 8;
    int mb = (group << 3) + rem % gs;
    int nb = rem / gs;
    const int m0 = mb * 128, n0 = nb * 128;

    const int tid  = threadIdx.x;
    const int w    = tid >> 6;
    const int lane = tid & 63;
    const int wm   = w & 1;
    const int wn   = w >> 1;
    const int lrow8 = lane >> 3;
    const int cs    = ((lane & 7) ^ lrow8) << 3;

    floatx4 acc[4][4];
#pragma unroll
    for (int i = 0; i < 4; ++i)
#pragma unroll
        for (int j = 0; j < 4; ++j) acc[i][j] = (floatx4){0.f, 0.f, 0.f, 0.f};

    const int mrow  = lane & 15;
    const int phys0 = ((lane >> 4) ^ (lane & 7)) << 3;
    const int phys1 = phys0 ^ 32;

    for (int k0 = 0; k0 < K; k0 += 64) {
#pragma unroll
        for (int i = 0; i < 4; ++i) {
            int rr = i * 32 + 8 * w + lrow8;
            GLDS16(A  + (size_t)(m0 + rr) * K + k0 + cs, As + (i * 32 + 8 * w) * 64);
        }
#pragma unroll
        for (int i = 0; i < 4; ++i) {
            int rr = i * 32 + 8 * w + lrow8;
            GLDS16(Bt + (size_t)(n0 + rr) * K + k0 + cs, Bs + (i * 32 + 8 * w) * 64);
        }
        __syncthreads();

#pragma unroll
        for (int h = 0; h < 2; ++h) {
            const int ph = h ? phys1 : phys0;
            short8 a[4], b[4];
#pragma unroll
            for (int nt = 0; nt < 4; ++nt)
                b[nt] = *(const short8*)&Bs[(wn * 64 + nt * 16 + mrow) * 64 + ph];
#pragma unroll
            for (int mt = 0; mt < 4; ++mt)
                a[mt] = *(const short8*)&As[(wm * 64 + mt * 16 + mrow) * 64 + ph];
#pragma unroll
            for (int mt = 0; mt < 4; ++mt)
#pragma unroll
                for (int nt = 0; nt < 4; ++nt)
                    acc[mt][nt] = __builtin_amdgcn_mfma_f32_16x16x32_bf16(a[mt], b[nt],
                                                                          acc[mt][nt], 0, 0, 0);
        }
        __syncthreads();
    }

    const int colb = n0 + wn * 64;
    const int r_quad = colb / dout;
    if (sn && r_quad >= R_REL) return;
    const int col = colb + (lane & 15);
    const int rb0 = m0 + wm * 64 + (lane >> 4) * 4;
#pragma unroll
    for (int mt = 0; mt < 4; ++mt) {
        float4 rsv;
        if (sn) rsv = *(const float4*)&sn[(size_t)r_quad * N_NODES + rb0 + mt * 16];
        else    rsv = (float4){1.f, 1.f, 1.f, 1.f};
        const float* rsp = (const float*)&rsv;
#pragma unroll
        for (int reg = 0; reg < 4; ++reg) {
            int row = rb0 + mt * 16 + reg;
            if (row < M) {
                float rs = rsp[reg];
#pragma unroll
                for (int nt = 0; nt < 4; ++nt)
                    C[(size_t)row * NdPad + col + nt * 16] = f2b(acc[mt][nt][reg] * rs);
            }
        }
    }
}

// ---------------- fused 3-relation ELL gather (dual-chunk; measured optimum) ------------
// Round-9 lesson: quad-chunk (64B/lane) regressed +14us — gather is LATENCY-bound;
// halving thread count cut the TLP that hides the dependent ell->row chain. Dual-chunk
// (32B/lane) is the measured optimum of {8B, 32B, 64B} per lane.
// mode==1: ell holds COMPACT row indices (pre-remapped), hr is [r][N][dout].
// mode==0: ell holds node indices, hr legacy row-major [s][3*dout] (stride S8).
__global__ void gather3_kernel(const unsigned short* __restrict__ hr, int S8, int d8,
                               const int* __restrict__ ell, const int* __restrict__ incnt,
                               const float* __restrict__ dn, const float* __restrict__ bsum,
                               unsigned short* __restrict__ outh,
                               int lgh, int total, int do_relu, int mode) {
    int i = blockIdx.x * blockDim.x + threadIdx.x;
    if (i >= total) return;
    int d = i >> lgh;
    int c = i & ((1 << lgh) - 1);
    int h8 = 1 << lgh;
    float a0[8] = {0.f, 0.f, 0.f, 0.f, 0.f, 0.f, 0.f, 0.f};
    float a1[8] = {0.f, 0.f, 0.f, 0.f, 0.f, 0.f, 0.f, 0.f};
    const ushort8* hr8 = (const ushort8*)hr;
#pragma unroll
    for (int r = 0; r < R_REL; ++r) {
        int nr = incnt[r * N_NODES + d];
        nr = nr < ELL_CAP ? nr : ELL_CAP;
        size_t base = (size_t)(r * N_NODES + d) << 5;
        float t0[8] = {0.f, 0.f, 0.f, 0.f, 0.f, 0.f, 0.f, 0.f};
        float t1[8] = {0.f, 0.f, 0.f, 0.f, 0.f, 0.f, 0.f, 0.f};
        for (int k = 0; k < nr; ++k) {
            int s = ell[base + k];
            size_t rowb;
            if (mode)
                rowb = ((size_t)(r * N_NODES + s)) * d8 + c;      // s = compact idx
            else
                rowb = (size_t)s * S8 + r * d8 + c;               // s = node idx
            ushort8 v0 = hr8[rowb];
            ushort8 v1 = hr8[rowb + h8];
#pragma unroll
            for (int j = 0; j < 8; ++j) { t0[j] += b2f(v0[j]); t1[j] += b2f(v1[j]); }
        }
        float dnd = dn[r * N_NODES + d];
#pragma unroll
        for (int j = 0; j < 8; ++j) { a0[j] += dnd * t0[j]; a1[j] += dnd * t1[j]; }
    }
    int f0 = c << 3, f1 = (c + h8) << 3;
#pragma unroll
    for (int j = 0; j < 8; ++j) { a0[j] += bsum[f0 + j]; a1[j] += bsum[f1 + j]; }
    if (do_relu) {
#pragma unroll
        for (int j = 0; j < 8; ++j) { a0[j] = fmaxf(a0[j], 0.f); a1[j] = fmaxf(a1[j], 0.f); }
    }
    ushort8 o0, o1;
#pragma unroll
    for (int j = 0; j < 8; ++j) { o0[j] = f2b(a0[j]); o1[j] = f2b(a1[j]); }
    size_t ob = ((size_t)d << (lgh + 1)) + c;
    ((ushort8*)outh)[ob]      = o0;
    ((ushort8*)outh)[ob + h8] = o1;
}

// ---------------- edge scores from UV ----------------
__global__ __launch_bounds__(256) void edge_score_kernel(
        const unsigned short* __restrict__ UV,
        const int* __restrict__ pos_src, const int* __restrict__ pos_dst,
        const int* __restrict__ neg_src, const int* __restrict__ neg_dst,
        const float* __restrict__ bp1, const float* __restrict__ Wp2,
        const float* __restrict__ bp2, float* __restrict__ outp) {
    __shared__ float sb[64], sw[64];
    int t = threadIdx.x;
    if (t < 64) { sb[t] = bp1[t]; sw[t] = Wp2[t]; }
    __syncthreads();
    int i = blockIdx.x * blockDim.x + t;
    if (i >= 2 * EP_EDGES) return;
    int s, d;
    if (i < EP_EDGES) { s = pos_src[i]; d = pos_dst[i]; }
    else              { s = neg_src[i - EP_EDGES]; d = neg_dst[i - EP_EDGES]; }
    const ushort8* UV8 = (const ushort8*)UV;
    float acc = bp2[0];
#pragma unroll
    for (int jv = 0; jv < 8; ++jv) {
        ushort8 u = UV8[(size_t)s * 16 + jv];
        ushort8 v = UV8[(size_t)d * 16 + 8 + jv];
#pragma unroll
        for (int j = 0; j < 8; ++j) {
            float z = b2f(u[j]) + b2f(v[j]) + sb[jv * 8 + j];
            acc = fmaf(fmaxf(z, 0.f), sw[jv * 8 + j], acc);
        }
    }
    outp[i] = acc;
}

extern "C" void kernel_launch(void* const* d_in, const int* in_sizes, int n_in,
                              void* d_out, int out_size, void* d_ws, size_t ws_size,
                              hipStream_t stream) {
    const float* x       = (const float*)d_in[0];
    const int*   rel_src = (const int*)d_in[1];
    const int*   rel_dst = (const int*)d_in[2];
    const int*   pos_src = (const int*)d_in[3];
    const int*   pos_dst = (const int*)d_in[4];
    const int*   neg_src = (const int*)d_in[5];
    const int*   neg_dst = (const int*)d_in[6];
    const float* W[4]    = {(const float*)d_in[7],  (const float*)d_in[9],
                            (const float*)d_in[11], (const float*)d_in[13]};
    const float* bias[4] = {(const float*)d_in[8],  (const float*)d_in[10],
                            (const float*)d_in[12], (const float*)d_in[14]};
    const float* Wp1 = (const float*)d_in[15];
    const float* bp1 = (const float*)d_in[16];
    const float* Wp2 = (const float*)d_in[17];
    const float* bp2 = (const float*)d_in[18];
    float* out = (float*)d_out;

    // workspace layout (bf16 buffers padded +128 rows for OOB tile reads, BM=128)
    size_t NP = (size_t)(N_NODES + 128);
    unsigned short* xb  = (unsigned short*)d_ws;          // NP x 512 (reused for UV later)
    unsigned short* h0  = xb + NP * 512;                  // NP x 512
    unsigned short* h1  = h0 + NP * 512;                  // NP x 256
    unsigned short* hr  = h1 + NP * 256;                  // 3*N*512 max (compact or fused C)
    unsigned short* Wt0 = hr + (size_t)R_REL * N_NODES * 512;
    unsigned short* Wt1 = Wt0 + 786432;
    unsigned short* Wt2 = Wt1 + 393216;
    unsigned short* Wt3 = Wt2 + 98304;
    unsigned short* But = Wt3 + 32768;                    // 128*64
    float* bsum = (float*)(But + 128 * 64);               // 960 summed biases
    float* sn   = bsum + 960;                             // full norms (L3 path + dn)
    float* dn   = sn + (size_t)R_REL * N_NODES;
    int* outcnt = (int*)(dn + (size_t)R_REL * N_NODES);
    int* incnt  = outcnt + (size_t)R_REL * N_NODES;
    int* csize  = incnt + (size_t)R_REL * N_NODES;        // 4 ints (3 used)
    int* ell    = csize + 4;                              // 3*N*32 ints (node idx)
    int* cmap   = ell + (size_t)R_REL * N_NODES * ELL_CAP;
    int* rlist  = cmap + (size_t)R_REL * N_NODES;
    float* snc  = (float*)(rlist + (size_t)R_REL * N_NODES);  // 3N + 128 pad
    int* ellc   = (int*)(snc + (size_t)R_REL * N_NODES + 128); // 3*N*32 ints (compact idx)
    unsigned short* UV = xb;                              // N x 128 (after layers done)
    const unsigned short* Wt[4] = {Wt0, Wt1, Wt2, Wt3};
    const int boff[4] = {0, 512, 768, 896};

    hipMemsetAsync(outcnt, 0, sizeof(int) * (2 * R_REL * N_NODES + 4), stream);
    count_fill_kernel<<<cdiv_h(R_REL * E_EDGES, 256), 256, 0, stream>>>(
        rel_src, rel_dst, outcnt, incnt, ell);

    aux_kernel<<<cdiv_h(AUX_CMP_BASE + AUX_CMP, 256), 256, 0, stream>>>(
        outcnt, sn, x, xb,
        W[0], W[1], W[2], W[3], Wp1, bias[0], bias[1], bias[2], bias[3],
        Wt0, Wt1, Wt2, Wt3, But, bsum, csize, cmap, rlist, snc);

    remap_kernel<<<cdiv_h(R_REL * N_NODES, 256), 256, 0, stream>>>(incnt, cmap, ell, ellc);

    const int dims[5] = {512, 512, 256, 128, 64};
    unsigned short* hbufs[4] = {h0, h1, h0, h1};
    const unsigned short* hcur = xb;
    for (int l = 0; l < 4; ++l) {
        int din = dims[l], dout = dims[l + 1];
        unsigned short* hnext = hbufs[l];
        // dual-chunk: threads per node = dout/16, each handling 2 ushort8 chunks
        int lgh = (dout == 512) ? 5 : (dout == 256) ? 4 : (dout == 128) ? 3 : 2;
        int total = N_NODES << lgh;
        if (l < 3) {   // compacted path (dout >= 128)
            dim3 grid(dout / 128, cdiv_h(N_NODES, 128), R_REL);
            gemm_bf16_cmp<<<grid, 256, 0, stream>>>(hcur, Wt[l], hr, snc, rlist, csize,
                                                    din, dout);
            gather3_kernel<<<cdiv_h(total, 256), 256, 0, stream>>>(
                hr, dout / 8, dout / 8, ellc, incnt, dn, bsum + boff[l], hnext, lgh, total,
                1, 1);
        } else {       // L3: dout=64 < BN -> legacy full path (NdPad=256)
            dim3 grid(256 / 128, cdiv_h(N_NODES, 128));
            gemm_bf16_fused<<<grid, 256, 0, stream>>>(hcur, Wt[l], hr, sn, N_NODES, din,
                                                      256, dout);
            gather3_kernel<<<cdiv_h(total, 256), 256, 0, stream>>>(
                hr, 256 / 8, dout / 8, ell, incnt, dn, bsum + boff[l], hnext, lgh, total,
                0, 0);
        }
        hcur = hnext;
    }

    // UV = h_final @ [Wp1_top | Wp1_bot]  (M=N, K=64, Nd=128)
    dim3 uvgrid(1, cdiv_h(N_NODES, 128));
    gemm_bf16_fused<<<uvgrid, 256, 0, stream>>>(hcur, But, UV, nullptr, N_NODES, 64, 128, 128);

    edge_score_kernel<<<cdiv_h(2 * EP_EDGES, 256), 256, 0, stream>>>(
        UV, pos_src, pos_dst, neg_src, neg_dst, bp1, Wp2, bp2, out);
}